// Round 3
// baseline (217.497 us; speedup 1.0000x reference)
//
#include <hip/hip_runtime.h>
#include <math.h>

#define TS 4
#define SDIM 128
#define PIX (SDIM * SDIM)
#define TEXW 512
#define TEXH 512
#define EPS 1e-9f
#define NTILE 64   // 8x8 tiles of 16x16 pixels
#define NSLICE 32  // face slices per tile -> raster grid = 64 x 32 blocks
#define ROUND 256  // faces staged per LDS round (== blockDim)
#define BBOX_MARGIN 1e-3f

// ---------------- Kernel 1: face setup + zbuf/cnt init ----------------------
__device__ inline void cross3(const float a[3], const float b[3], float o[3]) {
    o[0] = a[1] * b[2] - a[2] * b[1];
    o[1] = a[2] * b[0] - a[0] * b[2];
    o[2] = a[0] * b[1] - a[1] * b[0];
}

__global__ void setup_kernel(const float* __restrict__ verts,
                             const int* __restrict__ faces,
                             const void* __restrict__ azi_p,
                             const void* __restrict__ ele_p,
                             float4* __restrict__ fd,
                             unsigned long long* __restrict__ zbuf,
                             int* __restrict__ cnt, int F, int faceBlocks) {
#pragma clang fp contract(off)
    if ((int)blockIdx.x >= faceBlocks) {
        int t = (blockIdx.x - faceBlocks) * 256 + threadIdx.x;
        if (t < PIX) zbuf[t] = ~0ull;
        if ((int)blockIdx.x == faceBlocks && threadIdx.x < NTILE)
            cnt[threadIdx.x] = -1;  // counter protocol: starts at -1
        return;
    }
    int f = blockIdx.x * 256 + threadIdx.x;
    if (f >= F) return;
    // azi/ele are 1-element arrays; decode int-vs-float by bit pattern.
    int ai = *(const int*)azi_p;
    float az = (ai > -360000 && ai < 360000) ? (float)ai : *(const float*)azi_p;
    int ei = *(const int*)ele_p;
    float el = (ei > -360000 && ei < 360000) ? (float)ei : *(const float*)ele_p;
    float a = az * (float)(M_PI / 180.0);
    float e = el * (float)(M_PI / 180.0);
    float ca = cosf(a), sa = sinf(a);
    float ce = cosf(e), se = sinf(e);
    float eye[3];
    eye[0] = 2.732f * (ce * sa);
    eye[1] = 2.732f * se;
    eye[2] = 2.732f * ((-ce) * ca);
    float nrm = sqrtf(eye[0] * eye[0] + eye[1] * eye[1] + eye[2] * eye[2]);
    float zv[3] = { (-eye[0]) / nrm, (-eye[1]) / nrm, (-eye[2]) / nrm };
    float up[3] = { 0.0f, 1.0f, 0.0f };
    float xv[3];
    cross3(up, zv, xv);
    float xn = sqrtf(xv[0] * xv[0] + xv[1] * xv[1] + xv[2] * xv[2]);
    xv[0] /= xn; xv[1] /= xn; xv[2] /= xn;
    float yv[3];
    cross3(zv, xv, yv);
    float yn = sqrtf(yv[0] * yv[0] + yv[1] * yv[1] + yv[2] * yv[2]);
    yv[0] /= yn; yv[1] /= yn; yv[2] /= yn;

    float q[3][3];
    for (int k = 0; k < 3; ++k) {
        int vi = faces[f * 3 + k];
        float d0 = verts[vi * 3 + 0] - eye[0];
        float d1 = verts[vi * 3 + 1] - eye[1];
        float d2 = verts[vi * 3 + 2] - eye[2];
        q[k][0] = d0 * xv[0] + d1 * xv[1] + d2 * xv[2];
        q[k][1] = d0 * yv[0] + d1 * yv[1] + d2 * yv[2];
        q[k][2] = d0 * zv[0] + d1 * zv[1] + d2 * zv[2];
    }
    float e1x = q[1][0] - q[0][0], e1y = q[1][1] - q[0][1];
    float e2x = q[2][0] - q[0][0], e2y = q[2][1] - q[0][1];
    float det = e1x * e2y - e1y * e2x;
    bool valid = fabsf(det) > EPS;
    float inv = 1.0f / (valid ? det : 1.0f);
    // invalid det -> z=inf so depth is inf/NaN -> never selected
    float z0 = valid ? q[0][2] : INFINITY;
    float z1 = valid ? q[1][2] : INFINITY;
    float z2 = valid ? q[2][2] : INFINITY;
    fd[f * 3 + 0] = make_float4(q[0][0], q[0][1], e1x, e1y);
    fd[f * 3 + 1] = make_float4(e2x, e2y, inv, 0.0f);
    fd[f * 3 + 2] = make_float4(z0, z1, z2, 0.0f);
}

// monotone float->uint encoding (works for any sign; NaN excluded by caller)
__device__ inline unsigned int enc_depth(float d) {
    unsigned int u = __float_as_uint(d);
    return (u & 0x80000000u) ? ~u : (u | 0x80000000u);
}

// ---------------- Kernel 2: raster (bbox cull + LDS compact) + shade --------
// grid = (NTILE, NSLICE); block = 256 = one 16x16-pixel tile x one face chunk.
// After atomicMin, the LAST block per tile (agent-scope counter) shades it.
__global__ __launch_bounds__(256) void raster_shade_kernel(
    const float4* __restrict__ fd, const float* __restrict__ img,
    const float* __restrict__ grid, unsigned long long* __restrict__ zbuf,
    int* __restrict__ cnt, float* __restrict__ out, int F, int chunkFaces) {
#pragma clang fp contract(off)
    __shared__ float4 sA[ROUND];  // p0x p0y e1x e1y
    __shared__ float4 sB[ROUND];  // e2x e2y inv fid(bits)
    __shared__ float4 sZ[ROUND];  // z0 z1 z2 -
    __shared__ int scnt;
    __shared__ int slast;

    int tile = blockIdx.x;
    int slice = blockIdx.y;
    int tileX = tile & 7, tileY = tile >> 3;

    // tile NDC bounds (pixel centers) with conservative margin
    float xlo = (tileX * 16 + 0.5f) / 64.0f - 1.0f - BBOX_MARGIN;
    float xhi = (tileX * 16 + 15.5f) / 64.0f - 1.0f + BBOX_MARGIN;
    float yhi = 1.0f - (tileY * 16 + 0.5f) / 64.0f + BBOX_MARGIN;
    float ylo = 1.0f - (tileY * 16 + 15.5f) / 64.0f - BBOX_MARGIN;

    int j = tileX * 16 + (threadIdx.x & 15);
    int i = tileY * 16 + (threadIdx.x >> 4);
    float px = ((j + 0.5f) / 128.0f) * 2.0f - 1.0f;
    float py = 1.0f - ((i + 0.5f) / 128.0f) * 2.0f;

    float best = INFINITY;
    int bfid = 0x7fffffff;
    bool have = false;

    int f0 = slice * chunkFaces;
    int fend = min(f0 + chunkFaces, F);
    for (int base = f0; base < fend; base += ROUND) {
        __syncthreads();  // prev round's LDS readers done
        if (threadIdx.x == 0) scnt = 0;
        __syncthreads();
        int f = base + threadIdx.x;
        if (f < fend) {
            float4 A = fd[f * 3 + 0];
            float4 B = fd[f * 3 + 1];
            float4 C = fd[f * 3 + 2];
            float p1x = A.x + A.z, p1y = A.y + A.w;
            float p2x = A.x + B.x, p2y = A.y + B.y;
            float bxmin = fminf(A.x, fminf(p1x, p2x));
            float bxmax = fmaxf(A.x, fmaxf(p1x, p2x));
            float bymin = fminf(A.y, fminf(p1y, p2y));
            float bymax = fmaxf(A.y, fmaxf(p1y, p2y));
            if (bxmin <= xhi && bxmax >= xlo && bymin <= yhi && bymax >= ylo) {
                int pos = atomicAdd(&scnt, 1);
                B.w = __int_as_float(f);
                sA[pos] = A;
                sB[pos] = B;
                sZ[pos] = C;
            }
        }
        __syncthreads();
        int n = scnt;
        for (int s = 0; s < n; ++s) {
            float4 A = sA[s];
            float4 B = sB[s];
            float4 C = sZ[s];
            float dx = px - A.x, dy = py - A.y;
            float w1 = (dx * B.y - dy * B.x) * B.z;
            float w2 = (A.z * dy - A.w * dx) * B.z;
            float w0 = 1.0f - w1 - w2;
            bool inside = (w0 >= 0.0f) && (w1 >= 0.0f) && (w2 >= 0.0f);
            float depth = w0 * C.x + w1 * C.y + w2 * C.z;
            int fid = __float_as_int(B.w);
            // lexicographic (depth, fid): order-independent == first-min argmin
            if (inside && depth < INFINITY &&
                (depth < best || (depth == best && fid < bfid))) {
                best = depth;
                bfid = fid;
                have = true;
            }
        }
    }

    int p = i * SDIM + j;
    if (have) {
        unsigned long long pack =
            ((unsigned long long)enc_depth(best) << 32) | (unsigned int)bfid;
        atomicMin(&zbuf[p], pack);  // device-scope RMW, cross-XCD safe
    }

    // last-block-per-tile protocol (no spin: any arrival order is fine)
    __threadfence();
    __syncthreads();
    if (threadIdx.x == 0) {
        int old = __hip_atomic_fetch_add(&cnt[tile], 1, __ATOMIC_ACQ_REL,
                                         __HIP_MEMORY_SCOPE_AGENT);
        slast = (old == NSLICE - 2) ? 1 : 0;  // cnt starts at -1
    }
    __syncthreads();
    if (!slast) return;

    // ---- shade this tile (verbatim math from the verified shade_kernel) ----
    unsigned long long pack = __hip_atomic_load(&zbuf[p], __ATOMIC_RELAXED,
                                                __HIP_MEMORY_SCOPE_AGENT);
    int o = i * SDIM + (SDIM - 1 - j);  // x-flip ([..., ::-1])
    if (pack == ~0ull) {                // no finite hit -> zeros
        out[0 * PIX + o] = 0.0f;
        out[1 * PIX + o] = 0.0f;
        out[2 * PIX + o] = 0.0f;
        return;
    }
    int wfid = (int)(unsigned int)(pack & 0xffffffffu);
    // recompute barycentrics for winning face (bit-identical exprs)
    float4 A = fd[wfid * 3 + 0];
    float4 B = fd[wfid * 3 + 1];
    float dx = px - A.x, dy = py - A.y;
    float w1 = (dx * B.y - dy * B.x) * B.z;
    float w2 = (A.z * dy - A.w * dx) * B.z;
    float w0 = 1.0f - w1 - w2;
    int i0 = min(max((int)floorf(w0 * (float)TS), 0), TS - 1);
    int i1 = min(max((int)floorf(w1 * (float)TS), 0), TS - 1);
    int i2 = min(max((int)floorf(w2 * (float)TS), 0), TS - 1);
    int sidx = wfid * (TS * TS * TS) + i0 * 16 + i1 * 4 + i2;
    // on-demand bilinear sample (bit-identical to reference grid_sample)
    float gx = grid[2 * sidx], gy = grid[2 * sidx + 1];
    float x = (gx + 1.0f) * (TEXW * 0.5f) - 0.5f;
    float y = (gy + 1.0f) * (TEXH * 0.5f) - 0.5f;
    float x0f = floorf(x), y0f = floorf(y);
    float tx = x - x0f, ty = y - y0f;
    int x0 = (int)x0f, y0 = (int)y0f;
    float w00 = (1.0f - tx) * (1.0f - ty);
    float w10 = tx * (1.0f - ty);
    float w01 = (1.0f - tx) * ty;
    float w11 = tx * ty;
    bool vx0 = (x0 >= 0) && (x0 < TEXW);
    bool vx1 = (x0 + 1 >= 0) && (x0 + 1 < TEXW);
    bool vy0 = (y0 >= 0) && (y0 < TEXH);
    bool vy1 = (y0 + 1 >= 0) && (y0 + 1 < TEXH);
    int xc0 = min(max(x0, 0), TEXW - 1);
    int xc1 = min(max(x0 + 1, 0), TEXW - 1);
    int yc0 = min(max(y0, 0), TEXH - 1);
    int yc1 = min(max(y0 + 1, 0), TEXH - 1);
    float W00 = (vx0 && vy0) ? w00 : 0.0f;
    float W10 = (vx1 && vy0) ? w10 : 0.0f;
    float W01 = (vx0 && vy1) ? w01 : 0.0f;
    float W11 = (vx1 && vy1) ? w11 : 0.0f;
    for (int c = 0; c < 3; ++c) {
        const float* ic = img + c * (TEXH * TEXW);
        float acc = ic[yc0 * TEXW + xc0] * W00;
        acc = acc + ic[yc0 * TEXW + xc1] * W10;
        acc = acc + ic[yc1 * TEXW + xc0] * W01;
        acc = acc + ic[yc1 * TEXW + xc1] * W11;
        out[c * PIX + o] = acc;
    }
}

extern "C" void kernel_launch(void* const* d_in, const int* in_sizes, int n_in,
                              void* d_out, int out_size, void* d_ws,
                              size_t ws_size, hipStream_t stream) {
    const float* verts = (const float*)d_in[0];
    const float* img = (const float*)d_in[1];
    const float* grid = (const float*)d_in[2];
    const int* faces = (const int*)d_in[3];
    const void* azi = d_in[4];
    const void* ele = d_in[5];
    float* out = (float*)d_out;

    int F = in_sizes[3] / 3;  // faces

    char* ws = (char*)d_ws;
    size_t off = 0;
    float4* fd = (float4*)(ws + off);
    off += ((size_t)F * 3 * 16 + 255) & ~(size_t)255;
    unsigned long long* zbuf = (unsigned long long*)(ws + off);
    off += (size_t)PIX * 8;
    int* cnt = (int*)(ws + off);

    int faceBlocks = (F + 255) / 256;
    int zBlocks = (PIX + 255) / 256;
    int chunkFaces = (F + NSLICE - 1) / NSLICE;  // 63 for F=2000

    setup_kernel<<<faceBlocks + zBlocks, 256, 0, stream>>>(
        verts, faces, azi, ele, fd, zbuf, cnt, F, faceBlocks);
    raster_shade_kernel<<<dim3(NTILE, NSLICE), 256, 0, stream>>>(
        fd, img, grid, zbuf, cnt, out, F, chunkFaces);
}

// Round 4
// 121.476 us; speedup vs baseline: 1.7904x; 1.7904x over previous
//
#include <hip/hip_runtime.h>
#include <math.h>

#define TS 4
#define SDIM 128
#define PIX (SDIM * SDIM)
#define TEXW 512
#define TEXH 512
#define EPS 1e-9f
#define TILEW 8
#define TILEH 8
#define TXN (SDIM / TILEW)            // 16 tiles across
#define NTILE (TXN * (SDIM / TILEH))  // 256 tiles = 256 blocks
#define ROUND 256                     // faces staged per LDS round
#define NWAVE 4                       // 256 threads = 4 waves
#define BBOX_MARGIN 1e-3f

__device__ inline void cross3(const float a[3], const float b[3], float o[3]) {
    o[0] = a[1] * b[2] - a[2] * b[1];
    o[1] = a[2] * b[0] - a[0] * b[2];
    o[2] = a[0] * b[1] - a[1] * b[0];
}

// Camera basis — verbatim math from the verified setup_kernel.
__device__ inline void make_camera(const void* __restrict__ azi_p,
                                   const void* __restrict__ ele_p,
                                   float eye[3], float xv[3], float yv[3],
                                   float zv[3]) {
#pragma clang fp contract(off)
    // azi/ele are 1-element arrays; decode int-vs-float by bit pattern.
    int ai = *(const int*)azi_p;
    float az = (ai > -360000 && ai < 360000) ? (float)ai : *(const float*)azi_p;
    int ei = *(const int*)ele_p;
    float el = (ei > -360000 && ei < 360000) ? (float)ei : *(const float*)ele_p;
    float a = az * (float)(M_PI / 180.0);
    float e = el * (float)(M_PI / 180.0);
    float ca = cosf(a), sa = sinf(a);
    float ce = cosf(e), se = sinf(e);
    eye[0] = 2.732f * (ce * sa);
    eye[1] = 2.732f * se;
    eye[2] = 2.732f * ((-ce) * ca);
    float nrm = sqrtf(eye[0] * eye[0] + eye[1] * eye[1] + eye[2] * eye[2]);
    zv[0] = (-eye[0]) / nrm;
    zv[1] = (-eye[1]) / nrm;
    zv[2] = (-eye[2]) / nrm;
    float up[3] = { 0.0f, 1.0f, 0.0f };
    cross3(up, zv, xv);
    float xn = sqrtf(xv[0] * xv[0] + xv[1] * xv[1] + xv[2] * xv[2]);
    xv[0] /= xn; xv[1] /= xn; xv[2] /= xn;
    cross3(zv, xv, yv);
    float yn = sqrtf(yv[0] * yv[0] + yv[1] * yv[1] + yv[2] * yv[2]);
    yv[0] /= yn; yv[1] /= yn; yv[2] /= yn;
}

struct FD10 {
    float p0x, p0y, e1x, e1y, e2x, e2y, inv, z0, z1, z2;
};

// Face setup — verbatim math from the verified setup_kernel. Deterministic:
// every instantiation (staging and shade) yields bit-identical values.
__device__ inline FD10 face_setup(int f, const float* __restrict__ verts,
                                  const int* __restrict__ faces,
                                  const float eye[3], const float xv[3],
                                  const float yv[3], const float zv[3]) {
#pragma clang fp contract(off)
    float q[3][3];
    for (int k = 0; k < 3; ++k) {
        int vi = faces[f * 3 + k];
        float d0 = verts[vi * 3 + 0] - eye[0];
        float d1 = verts[vi * 3 + 1] - eye[1];
        float d2 = verts[vi * 3 + 2] - eye[2];
        q[k][0] = d0 * xv[0] + d1 * xv[1] + d2 * xv[2];
        q[k][1] = d0 * yv[0] + d1 * yv[1] + d2 * yv[2];
        q[k][2] = d0 * zv[0] + d1 * zv[1] + d2 * zv[2];
    }
    float e1x = q[1][0] - q[0][0], e1y = q[1][1] - q[0][1];
    float e2x = q[2][0] - q[0][0], e2y = q[2][1] - q[0][1];
    float det = e1x * e2y - e1y * e2x;
    bool valid = fabsf(det) > EPS;
    FD10 r;
    r.p0x = q[0][0];
    r.p0y = q[0][1];
    r.e1x = e1x;
    r.e1y = e1y;
    r.e2x = e2x;
    r.e2y = e2y;
    r.inv = 1.0f / (valid ? det : 1.0f);
    // invalid det -> z=inf so depth is inf/NaN -> never selected
    r.z0 = valid ? q[0][2] : INFINITY;
    r.z1 = valid ? q[1][2] : INFINITY;
    r.z2 = valid ? q[2][2] : INFINITY;
    return r;
}

// monotone float->uint encoding (works for any sign; NaN excluded by caller)
__device__ inline unsigned int enc_depth(float d) {
    unsigned int u = __float_as_uint(d);
    return (u & 0x80000000u) ? ~u : (u | 0x80000000u);
}

// ---------------- single fused kernel: setup + raster + shade ---------------
// grid = NTILE (256) blocks, 256 threads. Block b owns one 8x8-pixel tile and
// sees ALL faces: 8 rounds of {cooperative face setup, bbox cull, LDS
// compact}, 4 waves split survivors 4-way, per-lane u64 (depth,fid) argmin in
// registers, 4-way LDS combine, wave 0 shades. No global sync of any kind.
__global__ __launch_bounds__(256) void render_kernel(
    const float* __restrict__ verts, const int* __restrict__ faces,
    const float* __restrict__ img, const float* __restrict__ grid,
    const void* __restrict__ azi_p, const void* __restrict__ ele_p,
    float* __restrict__ out, int F) {
#pragma clang fp contract(off)
    __shared__ float4 sA[ROUND];  // p0x p0y e1x e1y
    __shared__ float4 sB[ROUND];  // e2x e2y inv fid(bits)
    __shared__ float4 sZ[ROUND];  // z0 z1 z2 -
    __shared__ unsigned long long sPart[NWAVE][TILEW * TILEH];
    __shared__ int scnt;

    int tile = blockIdx.x;
    int tileX = tile & (TXN - 1), tileY = tile >> 4;
    int lane = threadIdx.x & 63, wave = threadIdx.x >> 6;

    float eye[3], xv[3], yv[3], zv[3];
    make_camera(azi_p, ele_p, eye, xv, yv, zv);

    // tile NDC bounds (pixel centers) with conservative margin
    float xlo = (tileX * TILEW + 0.5f) / 64.0f - 1.0f - BBOX_MARGIN;
    float xhi = (tileX * TILEW + (TILEW - 0.5f)) / 64.0f - 1.0f + BBOX_MARGIN;
    float yhi = 1.0f - (tileY * TILEH + 0.5f) / 64.0f + BBOX_MARGIN;
    float ylo = 1.0f - (tileY * TILEH + (TILEH - 0.5f)) / 64.0f - BBOX_MARGIN;

    // pixel ownership: lane -> one pixel of the 8x8 tile (same for all waves)
    int j = tileX * TILEW + (lane & (TILEW - 1));
    int i = tileY * TILEH + (lane >> 3);
    float px = ((j + 0.5f) / 128.0f) * 2.0f - 1.0f;
    float py = 1.0f - ((i + 0.5f) / 128.0f) * 2.0f;

    unsigned long long pack = ~0ull;  // (enc_depth<<32)|fid, min = best

    for (int base = 0; base < F; base += ROUND) {
        __syncthreads();  // prev round's LDS readers done
        if (threadIdx.x == 0) scnt = 0;
        __syncthreads();
        int f = base + threadIdx.x;
        if (f < F) {
            FD10 r = face_setup(f, verts, faces, eye, xv, yv, zv);
            float p1x = r.p0x + r.e1x, p1y = r.p0y + r.e1y;
            float p2x = r.p0x + r.e2x, p2y = r.p0y + r.e2y;
            float bxmin = fminf(r.p0x, fminf(p1x, p2x));
            float bxmax = fmaxf(r.p0x, fmaxf(p1x, p2x));
            float bymin = fminf(r.p0y, fminf(p1y, p2y));
            float bymax = fmaxf(r.p0y, fmaxf(p1y, p2y));
            if (bxmin <= xhi && bxmax >= xlo && bymin <= yhi && bymax >= ylo) {
                // LDS compaction; order-independent argmin -> order irrelevant
                int pos = atomicAdd(&scnt, 1);
                sA[pos] = make_float4(r.p0x, r.p0y, r.e1x, r.e1y);
                sB[pos] = make_float4(r.e2x, r.e2y, r.inv, __int_as_float(f));
                sZ[pos] = make_float4(r.z0, r.z1, r.z2, 0.0f);
            }
        }
        __syncthreads();
        int n = scnt;
        // waves split survivors 4-way; per-wave reads are uniform (broadcast)
        for (int s = wave; s < n; s += NWAVE) {
            float4 A = sA[s];
            float4 B = sB[s];
            float4 C = sZ[s];
            float dx = px - A.x, dy = py - A.y;
            float w1 = (dx * B.y - dy * B.x) * B.z;
            float w2 = (A.z * dy - A.w * dx) * B.z;
            float w0 = 1.0f - w1 - w2;
            bool inside = (w0 >= 0.0f) && (w1 >= 0.0f) && (w2 >= 0.0f);
            float depth = w0 * C.x + w1 * C.y + w2 * C.z;
            // lexicographic (depth, fid) via monotone u64 pack — identical
            // semantics to the verified atomicMin-based combine.
            if (inside && depth < INFINITY) {
                unsigned long long cand =
                    ((unsigned long long)enc_depth(depth) << 32) |
                    (unsigned int)__float_as_int(B.w);
                pack = (cand < pack) ? cand : pack;
            }
        }
    }

    __syncthreads();
    sPart[wave][lane] = pack;
    __syncthreads();
    if (threadIdx.x >= TILEW * TILEH) return;

    unsigned long long best = sPart[0][threadIdx.x];
    for (int w = 1; w < NWAVE; ++w) {
        unsigned long long v = sPart[w][threadIdx.x];
        best = (v < best) ? v : best;
    }

    // ---- shade this pixel (verbatim math from the verified shade_kernel) ---
    int o = i * SDIM + (SDIM - 1 - j);  // x-flip ([..., ::-1])
    if (best == ~0ull) {                // no finite hit -> zeros
        out[0 * PIX + o] = 0.0f;
        out[1 * PIX + o] = 0.0f;
        out[2 * PIX + o] = 0.0f;
        return;
    }
    int wfid = (int)(unsigned int)(best & 0xffffffffu);
    // recompute winner's face data (bit-identical to staging-time values)
    FD10 r = face_setup(wfid, verts, faces, eye, xv, yv, zv);
    float dx = px - r.p0x, dy = py - r.p0y;
    float w1 = (dx * r.e2y - dy * r.e2x) * r.inv;
    float w2 = (r.e1x * dy - r.e1y * dx) * r.inv;
    float w0 = 1.0f - w1 - w2;
    int i0 = min(max((int)floorf(w0 * (float)TS), 0), TS - 1);
    int i1 = min(max((int)floorf(w1 * (float)TS), 0), TS - 1);
    int i2 = min(max((int)floorf(w2 * (float)TS), 0), TS - 1);
    int sidx = wfid * (TS * TS * TS) + i0 * 16 + i1 * 4 + i2;
    // on-demand bilinear sample (bit-identical to reference grid_sample)
    float gx = grid[2 * sidx], gy = grid[2 * sidx + 1];
    float x = (gx + 1.0f) * (TEXW * 0.5f) - 0.5f;
    float y = (gy + 1.0f) * (TEXH * 0.5f) - 0.5f;
    float x0f = floorf(x), y0f = floorf(y);
    float tx = x - x0f, ty = y - y0f;
    int x0 = (int)x0f, y0 = (int)y0f;
    float w00 = (1.0f - tx) * (1.0f - ty);
    float w10 = tx * (1.0f - ty);
    float w01 = (1.0f - tx) * ty;
    float w11 = tx * ty;
    bool vx0 = (x0 >= 0) && (x0 < TEXW);
    bool vx1 = (x0 + 1 >= 0) && (x0 + 1 < TEXW);
    bool vy0 = (y0 >= 0) && (y0 < TEXH);
    bool vy1 = (y0 + 1 >= 0) && (y0 + 1 < TEXH);
    int xc0 = min(max(x0, 0), TEXW - 1);
    int xc1 = min(max(x0 + 1, 0), TEXW - 1);
    int yc0 = min(max(y0, 0), TEXH - 1);
    int yc1 = min(max(y0 + 1, 0), TEXH - 1);
    float W00 = (vx0 && vy0) ? w00 : 0.0f;
    float W10 = (vx1 && vy0) ? w10 : 0.0f;
    float W01 = (vx0 && vy1) ? w01 : 0.0f;
    float W11 = (vx1 && vy1) ? w11 : 0.0f;
    for (int c = 0; c < 3; ++c) {
        const float* ic = img + c * (TEXH * TEXW);
        float acc = ic[yc0 * TEXW + xc0] * W00;
        acc = acc + ic[yc0 * TEXW + xc1] * W10;
        acc = acc + ic[yc1 * TEXW + xc0] * W01;
        acc = acc + ic[yc1 * TEXW + xc1] * W11;
        out[c * PIX + o] = acc;
    }
}

extern "C" void kernel_launch(void* const* d_in, const int* in_sizes, int n_in,
                              void* d_out, int out_size, void* d_ws,
                              size_t ws_size, hipStream_t stream) {
    const float* verts = (const float*)d_in[0];
    const float* img = (const float*)d_in[1];
    const float* grid = (const float*)d_in[2];
    const int* faces = (const int*)d_in[3];
    const void* azi = d_in[4];
    const void* ele = d_in[5];
    float* out = (float*)d_out;

    int F = in_sizes[3] / 3;  // faces

    render_kernel<<<NTILE, 256, 0, stream>>>(verts, faces, img, grid, azi, ele,
                                             out, F);
}

// Round 5
// 86.720 us; speedup vs baseline: 2.5080x; 1.4008x over previous
//
#include <hip/hip_runtime.h>
#include <math.h>

#define TS 4
#define SDIM 128
#define PIX (SDIM * SDIM)
#define TEXW 512
#define TEXH 512
#define EPS 1e-9f
#define TILEW 8
#define TILEH 8
#define TXN (SDIM / TILEW)            // 16 tiles across
#define NTILE (TXN * (SDIM / TILEH))  // 256 tiles = 256 blocks
#define BLK 1024                      // 16 waves per block
#define ROUND 1024                    // faces staged per LDS round (== BLK)
#define NWAVE (BLK / 64)              // 16
#define BBOX_MARGIN 1e-3f

__device__ inline void cross3(const float a[3], const float b[3], float o[3]) {
    o[0] = a[1] * b[2] - a[2] * b[1];
    o[1] = a[2] * b[0] - a[0] * b[2];
    o[2] = a[0] * b[1] - a[1] * b[0];
}

// Camera basis — verbatim math from the verified setup_kernel.
__device__ inline void make_camera(const void* __restrict__ azi_p,
                                   const void* __restrict__ ele_p,
                                   float eye[3], float xv[3], float yv[3],
                                   float zv[3]) {
#pragma clang fp contract(off)
    // azi/ele are 1-element arrays; decode int-vs-float by bit pattern.
    int ai = *(const int*)azi_p;
    float az = (ai > -360000 && ai < 360000) ? (float)ai : *(const float*)azi_p;
    int ei = *(const int*)ele_p;
    float el = (ei > -360000 && ei < 360000) ? (float)ei : *(const float*)ele_p;
    float a = az * (float)(M_PI / 180.0);
    float e = el * (float)(M_PI / 180.0);
    float ca = cosf(a), sa = sinf(a);
    float ce = cosf(e), se = sinf(e);
    eye[0] = 2.732f * (ce * sa);
    eye[1] = 2.732f * se;
    eye[2] = 2.732f * ((-ce) * ca);
    float nrm = sqrtf(eye[0] * eye[0] + eye[1] * eye[1] + eye[2] * eye[2]);
    zv[0] = (-eye[0]) / nrm;
    zv[1] = (-eye[1]) / nrm;
    zv[2] = (-eye[2]) / nrm;
    float up[3] = { 0.0f, 1.0f, 0.0f };
    cross3(up, zv, xv);
    float xn = sqrtf(xv[0] * xv[0] + xv[1] * xv[1] + xv[2] * xv[2]);
    xv[0] /= xn; xv[1] /= xn; xv[2] /= xn;
    cross3(zv, xv, yv);
    float yn = sqrtf(yv[0] * yv[0] + yv[1] * yv[1] + yv[2] * yv[2]);
    yv[0] /= yn; yv[1] /= yn; yv[2] /= yn;
}

struct FD10 {
    float p0x, p0y, e1x, e1y, e2x, e2y, inv, z0, z1, z2;
};

// Face setup — verbatim math from the verified setup_kernel. Deterministic:
// every instantiation (staging and shade) yields bit-identical values.
__device__ inline FD10 face_setup(int f, const float* __restrict__ verts,
                                  const int* __restrict__ faces,
                                  const float eye[3], const float xv[3],
                                  const float yv[3], const float zv[3]) {
#pragma clang fp contract(off)
    float q[3][3];
    for (int k = 0; k < 3; ++k) {
        int vi = faces[f * 3 + k];
        float d0 = verts[vi * 3 + 0] - eye[0];
        float d1 = verts[vi * 3 + 1] - eye[1];
        float d2 = verts[vi * 3 + 2] - eye[2];
        q[k][0] = d0 * xv[0] + d1 * xv[1] + d2 * xv[2];
        q[k][1] = d0 * yv[0] + d1 * yv[1] + d2 * yv[2];
        q[k][2] = d0 * zv[0] + d1 * zv[1] + d2 * zv[2];
    }
    float e1x = q[1][0] - q[0][0], e1y = q[1][1] - q[0][1];
    float e2x = q[2][0] - q[0][0], e2y = q[2][1] - q[0][1];
    float det = e1x * e2y - e1y * e2x;
    bool valid = fabsf(det) > EPS;
    FD10 r;
    r.p0x = q[0][0];
    r.p0y = q[0][1];
    r.e1x = e1x;
    r.e1y = e1y;
    r.e2x = e2x;
    r.e2y = e2y;
    r.inv = 1.0f / (valid ? det : 1.0f);
    // invalid det -> z=inf so depth is inf/NaN -> never selected
    r.z0 = valid ? q[0][2] : INFINITY;
    r.z1 = valid ? q[1][2] : INFINITY;
    r.z2 = valid ? q[2][2] : INFINITY;
    return r;
}

// monotone float->uint encoding (works for any sign; NaN excluded by caller)
__device__ inline unsigned int enc_depth(float d) {
    unsigned int u = __float_as_uint(d);
    return (u & 0x80000000u) ? ~u : (u | 0x80000000u);
}

// ---------------- single fused kernel: setup + raster + shade ---------------
// grid = NTILE (256) blocks x 1024 threads (16 waves). Block b owns one
// 8x8-pixel tile and sees ALL faces: 2 rounds of {cooperative face setup,
// bbox cull, LDS compact}, 16 waves split survivors 16-way (lane = pixel),
// per-lane u64 (depth,fid) argmin in registers, 16-way LDS combine, wave 0
// shades. No global sync, no atomicMin, no workspace.
__global__ __launch_bounds__(BLK) void render_kernel(
    const float* __restrict__ verts, const int* __restrict__ faces,
    const float* __restrict__ img, const float* __restrict__ grid,
    const void* __restrict__ azi_p, const void* __restrict__ ele_p,
    float* __restrict__ out, int F) {
#pragma clang fp contract(off)
    __shared__ float4 sA[ROUND];  // p0x p0y e1x e1y
    __shared__ float4 sB[ROUND];  // e2x e2y inv fid(bits)
    __shared__ float4 sZ[ROUND];  // z0 z1 z2 -
    __shared__ unsigned long long sPart[NWAVE][TILEW * TILEH];
    __shared__ int scnt;

    int tile = blockIdx.x;
    int tileX = tile & (TXN - 1), tileY = tile >> 4;
    int lane = threadIdx.x & 63, wave = threadIdx.x >> 6;

    float eye[3], xv[3], yv[3], zv[3];
    make_camera(azi_p, ele_p, eye, xv, yv, zv);

    // tile NDC bounds (pixel centers) with conservative margin
    float xlo = (tileX * TILEW + 0.5f) / 64.0f - 1.0f - BBOX_MARGIN;
    float xhi = (tileX * TILEW + (TILEW - 0.5f)) / 64.0f - 1.0f + BBOX_MARGIN;
    float yhi = 1.0f - (tileY * TILEH + 0.5f) / 64.0f + BBOX_MARGIN;
    float ylo = 1.0f - (tileY * TILEH + (TILEH - 0.5f)) / 64.0f - BBOX_MARGIN;

    // pixel ownership: lane -> one pixel of the 8x8 tile (same for all waves)
    int j = tileX * TILEW + (lane & (TILEW - 1));
    int i = tileY * TILEH + (lane >> 3);
    float px = ((j + 0.5f) / 128.0f) * 2.0f - 1.0f;
    float py = 1.0f - ((i + 0.5f) / 128.0f) * 2.0f;

    unsigned long long pack = ~0ull;  // (enc_depth<<32)|fid, min = best

    for (int base = 0; base < F; base += ROUND) {
        __syncthreads();  // prev round's LDS readers done
        if (threadIdx.x == 0) scnt = 0;
        __syncthreads();
        int f = base + threadIdx.x;
        if (f < F) {
            FD10 r = face_setup(f, verts, faces, eye, xv, yv, zv);
            float p1x = r.p0x + r.e1x, p1y = r.p0y + r.e1y;
            float p2x = r.p0x + r.e2x, p2y = r.p0y + r.e2y;
            float bxmin = fminf(r.p0x, fminf(p1x, p2x));
            float bxmax = fmaxf(r.p0x, fmaxf(p1x, p2x));
            float bymin = fminf(r.p0y, fminf(p1y, p2y));
            float bymax = fmaxf(r.p0y, fmaxf(p1y, p2y));
            if (bxmin <= xhi && bxmax >= xlo && bymin <= yhi && bymax >= ylo) {
                // LDS compaction; order-independent argmin -> order irrelevant
                int pos = atomicAdd(&scnt, 1);
                sA[pos] = make_float4(r.p0x, r.p0y, r.e1x, r.e1y);
                sB[pos] = make_float4(r.e2x, r.e2y, r.inv, __int_as_float(f));
                sZ[pos] = make_float4(r.z0, r.z1, r.z2, 0.0f);
            }
        }
        __syncthreads();
        int n = scnt;
        // waves split survivors 16-way; per-wave reads are uniform (broadcast)
        for (int s = wave; s < n; s += NWAVE) {
            float4 A = sA[s];
            float4 B = sB[s];
            float4 C = sZ[s];
            float dx = px - A.x, dy = py - A.y;
            float w1 = (dx * B.y - dy * B.x) * B.z;
            float w2 = (A.z * dy - A.w * dx) * B.z;
            float w0 = 1.0f - w1 - w2;
            bool inside = (w0 >= 0.0f) && (w1 >= 0.0f) && (w2 >= 0.0f);
            float depth = w0 * C.x + w1 * C.y + w2 * C.z;
            // lexicographic (depth, fid) via monotone u64 pack — identical
            // semantics to the verified atomicMin-based combine.
            if (inside && depth < INFINITY) {
                unsigned long long cand =
                    ((unsigned long long)enc_depth(depth) << 32) |
                    (unsigned int)__float_as_int(B.w);
                pack = (cand < pack) ? cand : pack;
            }
        }
    }

    __syncthreads();
    sPart[wave][lane] = pack;
    __syncthreads();
    if (threadIdx.x >= TILEW * TILEH) return;

    unsigned long long best = sPart[0][threadIdx.x];
    for (int w = 1; w < NWAVE; ++w) {
        unsigned long long v = sPart[w][threadIdx.x];
        best = (v < best) ? v : best;
    }

    // ---- shade this pixel (verbatim math from the verified shade_kernel) ---
    int o = i * SDIM + (SDIM - 1 - j);  // x-flip ([..., ::-1])
    if (best == ~0ull) {                // no finite hit -> zeros
        out[0 * PIX + o] = 0.0f;
        out[1 * PIX + o] = 0.0f;
        out[2 * PIX + o] = 0.0f;
        return;
    }
    int wfid = (int)(unsigned int)(best & 0xffffffffu);
    // recompute winner's face data (bit-identical to staging-time values)
    FD10 r = face_setup(wfid, verts, faces, eye, xv, yv, zv);
    float dx = px - r.p0x, dy = py - r.p0y;
    float w1 = (dx * r.e2y - dy * r.e2x) * r.inv;
    float w2 = (r.e1x * dy - r.e1y * dx) * r.inv;
    float w0 = 1.0f - w1 - w2;
    int i0 = min(max((int)floorf(w0 * (float)TS), 0), TS - 1);
    int i1 = min(max((int)floorf(w1 * (float)TS), 0), TS - 1);
    int i2 = min(max((int)floorf(w2 * (float)TS), 0), TS - 1);
    int sidx = wfid * (TS * TS * TS) + i0 * 16 + i1 * 4 + i2;
    // on-demand bilinear sample (bit-identical to reference grid_sample)
    float gx = grid[2 * sidx], gy = grid[2 * sidx + 1];
    float x = (gx + 1.0f) * (TEXW * 0.5f) - 0.5f;
    float y = (gy + 1.0f) * (TEXH * 0.5f) - 0.5f;
    float x0f = floorf(x), y0f = floorf(y);
    float tx = x - x0f, ty = y - y0f;
    int x0 = (int)x0f, y0 = (int)y0f;
    float w00 = (1.0f - tx) * (1.0f - ty);
    float w10 = tx * (1.0f - ty);
    float w01 = (1.0f - tx) * ty;
    float w11 = tx * ty;
    bool vx0 = (x0 >= 0) && (x0 < TEXW);
    bool vx1 = (x0 + 1 >= 0) && (x0 + 1 < TEXW);
    bool vy0 = (y0 >= 0) && (y0 < TEXH);
    bool vy1 = (y0 + 1 >= 0) && (y0 + 1 < TEXH);
    int xc0 = min(max(x0, 0), TEXW - 1);
    int xc1 = min(max(x0 + 1, 0), TEXW - 1);
    int yc0 = min(max(y0, 0), TEXH - 1);
    int yc1 = min(max(y0 + 1, 0), TEXH - 1);
    float W00 = (vx0 && vy0) ? w00 : 0.0f;
    float W10 = (vx1 && vy0) ? w10 : 0.0f;
    float W01 = (vx0 && vy1) ? w01 : 0.0f;
    float W11 = (vx1 && vy1) ? w11 : 0.0f;
    for (int c = 0; c < 3; ++c) {
        const float* ic = img + c * (TEXH * TEXW);
        float acc = ic[yc0 * TEXW + xc0] * W00;
        acc = acc + ic[yc0 * TEXW + xc1] * W10;
        acc = acc + ic[yc1 * TEXW + xc0] * W01;
        acc = acc + ic[yc1 * TEXW + xc1] * W11;
        out[c * PIX + o] = acc;
    }
}

extern "C" void kernel_launch(void* const* d_in, const int* in_sizes, int n_in,
                              void* d_out, int out_size, void* d_ws,
                              size_t ws_size, hipStream_t stream) {
    const float* verts = (const float*)d_in[0];
    const float* img = (const float*)d_in[1];
    const float* grid = (const float*)d_in[2];
    const int* faces = (const int*)d_in[3];
    const void* azi = d_in[4];
    const void* ele = d_in[5];
    float* out = (float*)d_out;

    int F = in_sizes[3] / 3;  // faces

    render_kernel<<<NTILE, BLK, 0, stream>>>(verts, faces, img, grid, azi, ele,
                                             out, F);
}